// Round 8
// baseline (963.282 us; speedup 1.0000x reference)
//
#include <hip/hip_runtime.h>
#include <hip/hip_bf16.h>

typedef __hip_bfloat16 bf16;
typedef __attribute__((ext_vector_type(8))) short bf16x8;
typedef __attribute__((ext_vector_type(8))) unsigned short u16x8;
typedef __attribute__((ext_vector_type(4))) float f32x4;

__device__ __forceinline__ float b2f(unsigned short u) {
  return __uint_as_float(((unsigned)u) << 16);
}
__device__ __forceinline__ unsigned short f2b(float x) {
  bf16 h = __float2bfloat16(x);
  return *reinterpret_cast<unsigned short*>(&h);
}

// ============== passA (dst coarse hist) + dtype probe fused ==============
__global__ void k_passA(const int* __restrict__ dst, int E, int nbuck,
                        int* __restrict__ counts,
                        const unsigned short* __restrict__ raw, int* __restrict__ flag) {
  if (blockIdx.x == 256) {
    __shared__ int sbad, snz;
    const int t = threadIdx.x;
    if (t == 0) { sbad = 0; snz = 0; }
    __syncthreads();
    const unsigned short u = raw[t];
    const float a = fabsf(b2f(u));
    if (!(a < 100.f)) atomicAdd(&sbad, 1);
    if (((t & 1) == 0) && u != 0) atomicAdd(&snz, 1);
    __syncthreads();
    if (t == 0) flag[0] = (sbad == 0 && snz > 0) ? 1 : 0;
    return;
  }
  extern __shared__ int lh[];
  const int t = threadIdx.x;
  for (int k = t; k < nbuck; k += 256) lh[k] = 0;
  __syncthreads();
  const int chunk = (E + 255) / 256;
  const int s = blockIdx.x * chunk;
  const int e = min(E, s + chunk);
  for (int i = s + t; i < e; i += 256) atomicAdd(&lh[dst[i] >> 8], 1);
  __syncthreads();
  for (int k = t; k < nbuck; k += 256) counts[k * 256 + blockIdx.x] = lh[k];
}

__global__ void k_scan1(const int* __restrict__ a, int M, int* __restrict__ bsums) {
  __shared__ int sdata[256];
  int i = blockIdx.x * 256 + threadIdx.x;
  int v = (i < M) ? a[i] : 0;
  sdata[threadIdx.x] = v;
  __syncthreads();
  for (int s = 128; s > 0; s >>= 1) {
    if (threadIdx.x < s) sdata[threadIdx.x] += sdata[threadIdx.x + s];
    __syncthreads();
  }
  if (threadIdx.x == 0) bsums[blockIdx.x] = sdata[0];
}

__global__ void k_scan2(int* __restrict__ bsums, int nb) {
  __shared__ int s[512];
  const int t = threadIdx.x;
  const int v = (t < nb) ? bsums[t] : 0;
  s[t] = v;
  __syncthreads();
  for (int off = 1; off < 512; off <<= 1) {
    int u = (t >= off) ? s[t - off] : 0;
    __syncthreads();
    s[t] += u;
    __syncthreads();
  }
  if (t < nb) bsums[t] = s[t] - v;  // exclusive
}

__global__ void k_scan3(int* __restrict__ a, int M, const int* __restrict__ bsums) {
  __shared__ int sdata[256];
  int i = blockIdx.x * 256 + threadIdx.x;
  int v = (i < M) ? a[i] : 0;
  sdata[threadIdx.x] = v;
  __syncthreads();
  for (int off = 1; off < 256; off <<= 1) {
    int t = (threadIdx.x >= off) ? sdata[threadIdx.x - off] : 0;
    __syncthreads();
    sdata[threadIdx.x] += t;
    __syncthreads();
  }
  if (i < M) a[i] = bsums[blockIdx.x] + sdata[threadIdx.x] - v;  // exclusive
}

// passC: scatter packed (src | (dst&255)<<20) into bucket-grouped tmp.
// FUSED deg_out atomic drain (round-6 proven pairing: both fabric-side).
__global__ void k_passC(const int* __restrict__ src, const int* __restrict__ dst, int E,
                        int nbuck, const int* __restrict__ S, int* __restrict__ tmp,
                        int* __restrict__ deg_out) {
  extern __shared__ int cur[];
  const int t = threadIdx.x;
  for (int k = t; k < nbuck; k += 256) cur[k] = S[k * 256 + blockIdx.x];
  __syncthreads();
  const int chunk = (E + 255) / 256;
  const int s = blockIdx.x * chunk;
  const int e = min(E, s + chunk);
  for (int i = s + t; i < e; i += 256) {
    const int sv = src[i];
    const int d = dst[i];
    atomicAdd(&deg_out[sv], 1);
    const int pos = atomicAdd(&cur[d >> 8], 1);
    tmp[pos] = sv | ((d & 255) << 20);
  }
}

// ============== passD: CSR finalize with per-(row,src-tile) segments ==============
// rowTile[n*8+t] = start of src-tile t within row n (t in [0,8); tiles >= NT are
// empty so rowTile[n*8+NT..7] == row end, giving free end boundaries).
__global__ void k_passD(const int* __restrict__ tmp, const int* __restrict__ S,
                        int nbuck, int N, int E, const int* __restrict__ deg_out,
                        int* __restrict__ rowTile, int* __restrict__ edgeSrc,
                        float* __restrict__ ns, float* __restrict__ nd, int TSH) {
  __shared__ int h2[256 * 8];  // per-(localnode,tile) counts, then cursors
  __shared__ int ex[256];
  const int t = threadIdx.x;
  const int k = blockIdx.x;
  const int bs = S[k * 256];
  const int be = (k + 1 < nbuck) ? S[(k + 1) * 256] : E;
  for (int j = t; j < 2048; j += 256) h2[j] = 0;
  __syncthreads();
  for (int i = bs + t; i < be; i += 256) {
    const int v = tmp[i];
    const int tile = (v & 0xFFFFF) >> TSH;
    atomicAdd(&h2[(v >> 20) * 8 + tile], 1);
  }
  __syncthreads();
  int hl[8];
  int cnt = 0;
#pragma unroll
  for (int j = 0; j < 8; ++j) { hl[j] = h2[t * 8 + j]; cnt += hl[j]; }
  ex[t] = cnt;
  __syncthreads();
  for (int off = 1; off < 256; off <<= 1) {
    int u = (t >= off) ? ex[t - off] : 0;
    __syncthreads();
    ex[t] += u;
    __syncthreads();
  }
  const int node = k * 256 + t;
  int run = bs + ex[t] - cnt;  // row base
  if (node < N) {
    nd[node] = rsqrtf((float)(cnt > 0 ? cnt : 1));
    int dov = deg_out[node];
    if (dov <= 0) dov = 1;
    ns[node] = rsqrtf((float)dov);
  }
#pragma unroll
  for (int j = 0; j < 8; ++j) {
    if (node < N) rowTile[(size_t)node * 8 + j] = run;
    h2[t * 8 + j] = run;  // cursor
    run += hl[j];
  }
  __syncthreads();
  for (int i = bs + t; i < be; i += 256) {
    const int v = tmp[i];
    const int sv = v & 0xFFFFF;
    const int pos = atomicAdd(&h2[(v >> 20) * 8 + (sv >> TSH)], 1);
    edgeSrc[pos] = sv;
  }
}

// ---------------- MFMA GEMM: out[r][c] = bf16( [ns[r]*] sum_k h[r][k]*W[k][c] ) ------
template <int K, bool FIRST, bool SCALE>
__global__ void k_gemm(const void* __restrict__ hin, const void* __restrict__ Wv,
                       const int* __restrict__ flag, const float* __restrict__ norm_src,
                       int N, unsigned short* __restrict__ out) {
  const bool isb = (*flag != 0);
  const int lane = threadIdx.x & 63;
  const int quad = lane >> 4;
  const int l16 = lane & 15;
  constexpr int KT = K / 32;

  bf16x8 Bf[KT][4];
  {
    const unsigned short* Wus = (const unsigned short*)Wv;
    const float* Wf = (const float*)Wv;
#pragma unroll
    for (int kt = 0; kt < KT; ++kt)
#pragma unroll
      for (int nt = 0; nt < 4; ++nt)
#pragma unroll
        for (int j = 0; j < 8; ++j) {
          const int k = kt * 32 + quad * 8 + j;
          const int n = nt * 16 + l16;
          const float w = isb ? b2f(Wus[k * 64 + n]) : Wf[k * 64 + n];
          Bf[kt][nt][j] = (short)f2b(w);
        }
  }
  const int wid = (blockIdx.x * blockDim.x + threadIdx.x) >> 6;
  const int nw = (gridDim.x * blockDim.x) >> 6;
  const int G = (N + 15) >> 4;
  for (int g = wid; g < G; g += nw) {
    int rowA = (g << 4) + l16;
    if (rowA >= N) rowA = N - 1;
    f32x4 acc[4] = {{0.f, 0.f, 0.f, 0.f}, {0.f, 0.f, 0.f, 0.f},
                    {0.f, 0.f, 0.f, 0.f}, {0.f, 0.f, 0.f, 0.f}};
#pragma unroll
    for (int kt = 0; kt < KT; ++kt) {
      const int koff = kt * 32 + quad * 8;
      bf16x8 Af;
      if (FIRST && !isb) {
        const float* hp = (const float*)hin + (size_t)rowA * K + koff;
        const float4 u0 = *(const float4*)hp;
        const float4 u1 = *(const float4*)(hp + 4);
        Af[0] = (short)f2b(u0.x); Af[1] = (short)f2b(u0.y);
        Af[2] = (short)f2b(u0.z); Af[3] = (short)f2b(u0.w);
        Af[4] = (short)f2b(u1.x); Af[5] = (short)f2b(u1.y);
        Af[6] = (short)f2b(u1.z); Af[7] = (short)f2b(u1.w);
      } else {
        Af = *(const bf16x8*)((const unsigned short*)hin + (size_t)rowA * K + koff);
      }
      acc[0] = __builtin_amdgcn_mfma_f32_16x16x32_bf16(Af, Bf[kt][0], acc[0], 0, 0, 0);
      acc[1] = __builtin_amdgcn_mfma_f32_16x16x32_bf16(Af, Bf[kt][1], acc[1], 0, 0, 0);
      acc[2] = __builtin_amdgcn_mfma_f32_16x16x32_bf16(Af, Bf[kt][2], acc[2], 0, 0, 0);
      acc[3] = __builtin_amdgcn_mfma_f32_16x16x32_bf16(Af, Bf[kt][3], acc[3], 0, 0, 0);
    }
    const int rowD = (g << 4) + quad * 4;
#pragma unroll
    for (int r = 0; r < 4; ++r) {
      if (rowD + r < N) {
        const float f = SCALE ? norm_src[rowD + r] : 1.0f;
        const size_t o = (size_t)(rowD + r) * 64 + l16;
#pragma unroll
        for (int nt = 0; nt < 4; ++nt)
          out[o + nt * 16] = f2b(SCALE ? acc[nt][r] * f : acc[nt][r]);
      }
    }
  }
}

// ============== tiled aggregation: 16 nodes/wave, src-tile outer loop ==============
// lane: eo = lane>>5 (2 parallel edges), cp = lane&31 (column pair 2cp,2cp+1).
// All concurrent waves sweep src-tiles in the same order -> each ~2MB proj slice
// is L2-resident on every XCD while it's being gathered.
template <bool LAST>
__global__ void k_aggT(const unsigned short* __restrict__ proj,
                       const int* __restrict__ edgeSrc, const int* __restrict__ rowTile,
                       const float* __restrict__ norm_dst, const float* __restrict__ norm_src,
                       const void* __restrict__ bias, const int* __restrict__ flag,
                       int N, int NT, void* __restrict__ outp) {
  const bool isb = (*flag != 0);
  const int lane = threadIdx.x & 63;
  const int eo = lane >> 5;
  const int cp = lane & 31;
  float bc0, bc1;
  if (isb) {
    const unsigned short* bb = (const unsigned short*)bias;
    bc0 = b2f(bb[cp * 2]); bc1 = b2f(bb[cp * 2 + 1]);
  } else {
    const float* bb = (const float*)bias;
    bc0 = bb[cp * 2]; bc1 = bb[cp * 2 + 1];
  }
  const int wave = (blockIdx.x * blockDim.x + threadIdx.x) >> 6;
  const int base = wave * 16;
  if (base >= N) return;
  float a0[16], a1[16];
#pragma unroll
  for (int i = 0; i < 16; ++i) { a0[i] = 0.f; a1[i] = 0.f; }
  for (int t = 0; t < NT; ++t) {
#pragma unroll
    for (int i = 0; i < 16; ++i) {
      const int n = base + i;
      if (n < N) {
        const int rt0 = rowTile[(size_t)n * 8 + t];
        const int rt1 = rowTile[(size_t)n * 8 + t + 1];
        for (int p = rt0 + eo; p < rt1; p += 2) {
          const int sn = edgeSrc[p];
          const ushort2 v = *(const ushort2*)(proj + (size_t)sn * 64 + cp * 2);
          a0[i] += b2f(v.x);
          a1[i] += b2f(v.y);
        }
      }
    }
  }
#pragma unroll
  for (int i = 0; i < 16; ++i) {
    a0[i] += __shfl_xor(a0[i], 32, 64);
    a1[i] += __shfl_xor(a1[i], 32, 64);
  }
  if (eo == 0) {
#pragma unroll
    for (int i = 0; i < 16; ++i) {
      const int n = base + i;
      if (n < N) {
        const float nd = norm_dst[n];
        float r0 = fmaxf(fmaf(a0[i], nd, bc0), 0.f);
        float r1 = fmaxf(fmaf(a1[i], nd, bc1), 0.f);
        if (!LAST) {
          const float e = norm_src[n];
          r0 *= e; r1 *= e;
        }
        if (LAST && !isb) {
          float2 o; o.x = r0; o.y = r1;
          *(float2*)((float*)outp + (size_t)n * 64 + cp * 2) = o;
        } else {
          ushort2 o; o.x = f2b(r0); o.y = f2b(r1);
          *(ushort2*)((unsigned short*)outp + (size_t)n * 64 + cp * 2) = o;
        }
      }
    }
  }
}

extern "C" void kernel_launch(void* const* d_in, const int* in_sizes, int n_in,
                              void* d_out, int out_size, void* d_ws, size_t ws_size,
                              hipStream_t stream) {
  const void* features = d_in[0];
  const void* W0 = d_in[1];
  const void* b0 = d_in[2];
  const void* W1 = d_in[3];
  const void* b1 = d_in[4];
  const void* W2 = d_in[5];
  const void* b2 = d_in[6];
  const int* src = (const int*)d_in[7];
  const int* dst = (const int*)d_in[8];
  const int N = in_sizes[0] / 128;
  const int E = in_sizes[7];
  const int NBUCK = (N + 255) >> 8;
  const int M = NBUCK * 256;
  // src-tile shift: largest tiles with NT <= 7 (rowTile has 8 slots/node)
  int TSH = 10;
  while (((N - 1) >> TSH) > 6) TSH++;
  const int NT = ((N - 1) >> TSH) + 1;

  char* w = (char*)d_ws;
  size_t off = 0;
  auto alloc = [&](size_t bytes) {
    void* p = w + off;
    off = (off + bytes + 255) & ~(size_t)255;
    return p;
  };
  int* deg_out = (int*)alloc((size_t)N * 4);
  const size_t zero_bytes = off;  // only deg_out needs zeroing
  int* flag = (int*)alloc(4);
  int* counts = (int*)alloc((size_t)M * 4);
  int* bsums = (int*)alloc(512 * 4);
  float* norm_src = (float*)alloc((size_t)N * 4);
  float* norm_dst = (float*)alloc((size_t)N * 4);
  int* tmp = (int*)alloc((size_t)E * 4);
  int* edgeSrc = (int*)alloc((size_t)E * 4);
  int* rowTile = (int*)alloc((size_t)N * 8 * 4);
  unsigned short* projA = (unsigned short*)alloc((size_t)N * 64 * 2);  // bf16
  unsigned short* hB = (unsigned short*)d_out;  // inter-layer h (bf16) in d_out

  hipMemsetAsync(d_ws, 0, zero_bytes, stream);

  const size_t lds_nb = (size_t)NBUCK * 4;
  const int GB = ((N + 15) / 16 + 3) / 4;

  // CSR build
  k_passA<<<257, 256, lds_nb, stream>>>(dst, E, NBUCK, counts,
                                        (const unsigned short*)features, flag);
  const int NB2 = (M + 255) / 256;  // == NBUCK
  k_scan1<<<NB2, 256, 0, stream>>>(counts, M, bsums);
  k_scan2<<<1, 512, 0, stream>>>(bsums, NB2);
  k_scan3<<<NB2, 256, 0, stream>>>(counts, M, bsums);
  k_passC<<<256, 256, lds_nb, stream>>>(src, dst, E, NBUCK, counts, tmp, deg_out);
  k_passD<<<NBUCK, 256, 0, stream>>>(tmp, counts, NBUCK, N, E, deg_out,
                                     rowTile, edgeSrc, norm_src, norm_dst, TSH);

  const int AB = ((N + 15) / 16 + 3) / 4;  // 16 nodes/wave, 4 waves/block
  // layer 0 (ns folded into gemm0 epilogue)
  k_gemm<128, true, true><<<GB, 256, 0, stream>>>(features, W0, flag, norm_src, N, projA);
  k_aggT<false><<<AB, 256, 0, stream>>>(projA, edgeSrc, rowTile, norm_dst, norm_src, b0, flag, N, NT, hB);
  // layer 1 (h pre-scaled by ns in agg epilogue)
  k_gemm<64, false, false><<<GB, 256, 0, stream>>>(hB, W1, flag, nullptr, N, projA);
  k_aggT<false><<<AB, 256, 0, stream>>>(projA, edgeSrc, rowTile, norm_dst, norm_src, b1, flag, N, NT, hB);
  // layer 2 -> d_out
  k_gemm<64, false, false><<<GB, 256, 0, stream>>>(hB, W2, flag, nullptr, N, projA);
  k_aggT<true><<<AB, 256, 0, stream>>>(projA, edgeSrc, rowTile, norm_dst, norm_src, b2, flag, N, NT, d_out);
}

// Round 9
// 535.034 us; speedup vs baseline: 1.8004x; 1.8004x over previous
//
#include <hip/hip_runtime.h>
#include <hip/hip_bf16.h>

typedef __hip_bfloat16 bf16;
typedef __attribute__((ext_vector_type(8))) short bf16x8;
typedef __attribute__((ext_vector_type(4))) float f32x4;

__device__ __forceinline__ float b2f(unsigned short u) {
  return __uint_as_float(((unsigned)u) << 16);
}
__device__ __forceinline__ unsigned short f2b(float x) {
  bf16 h = __float2bfloat16(x);
  return *reinterpret_cast<unsigned short*>(&h);
}

// ============== passA (dst coarse hist) + dtype probe fused ==============
__global__ void k_passA(const int* __restrict__ dst, int E, int nbuck,
                        int* __restrict__ counts,
                        const unsigned short* __restrict__ raw, int* __restrict__ flag) {
  if (blockIdx.x == 256) {
    __shared__ int sbad, snz;
    const int t = threadIdx.x;
    if (t == 0) { sbad = 0; snz = 0; }
    __syncthreads();
    const unsigned short u = raw[t];
    const float a = fabsf(b2f(u));
    if (!(a < 100.f)) atomicAdd(&sbad, 1);
    if (((t & 1) == 0) && u != 0) atomicAdd(&snz, 1);
    __syncthreads();
    if (t == 0) flag[0] = (sbad == 0 && snz > 0) ? 1 : 0;
    return;
  }
  extern __shared__ int lh[];
  const int t = threadIdx.x;
  for (int k = t; k < nbuck; k += 256) lh[k] = 0;
  __syncthreads();
  const int chunk = (E + 255) / 256;
  const int s = blockIdx.x * chunk;
  const int e = min(E, s + chunk);
  for (int i = s + t; i < e; i += 256) atomicAdd(&lh[dst[i] >> 8], 1);
  __syncthreads();
  for (int k = t; k < nbuck; k += 256) counts[k * 256 + blockIdx.x] = lh[k];
}

__global__ void k_scan1(const int* __restrict__ a, int M, int* __restrict__ bsums) {
  __shared__ int sdata[256];
  int i = blockIdx.x * 256 + threadIdx.x;
  int v = (i < M) ? a[i] : 0;
  sdata[threadIdx.x] = v;
  __syncthreads();
  for (int s = 128; s > 0; s >>= 1) {
    if (threadIdx.x < s) sdata[threadIdx.x] += sdata[threadIdx.x + s];
    __syncthreads();
  }
  if (threadIdx.x == 0) bsums[blockIdx.x] = sdata[0];
}

__global__ void k_scan2(int* __restrict__ bsums, int nb, int* __restrict__ rowStart,
                        int N, int E) {
  __shared__ int s[512];
  const int t = threadIdx.x;
  const int v = (t < nb) ? bsums[t] : 0;
  s[t] = v;
  __syncthreads();
  for (int off = 1; off < 512; off <<= 1) {
    int u = (t >= off) ? s[t - off] : 0;
    __syncthreads();
    s[t] += u;
    __syncthreads();
  }
  if (t < nb) bsums[t] = s[t] - v;  // exclusive
  if (t == 0) rowStart[N] = E;
}

__global__ void k_scan3(int* __restrict__ a, int M, const int* __restrict__ bsums) {
  __shared__ int sdata[256];
  int i = blockIdx.x * 256 + threadIdx.x;
  int v = (i < M) ? a[i] : 0;
  sdata[threadIdx.x] = v;
  __syncthreads();
  for (int off = 1; off < 256; off <<= 1) {
    int t = (threadIdx.x >= off) ? sdata[threadIdx.x - off] : 0;
    __syncthreads();
    sdata[threadIdx.x] += t;
    __syncthreads();
  }
  if (i < M) a[i] = bsums[blockIdx.x] + sdata[threadIdx.x] - v;  // exclusive
}

// passC: scatter packed (src | (dst&255)<<20) into bucket-grouped tmp.
// FUSED deg_out atomic drain (round-6 proven pairing: both fabric-side).
__global__ void k_passC(const int* __restrict__ src, const int* __restrict__ dst, int E,
                        int nbuck, const int* __restrict__ S, int* __restrict__ tmp,
                        int* __restrict__ deg_out) {
  extern __shared__ int cur[];
  const int t = threadIdx.x;
  for (int k = t; k < nbuck; k += 256) cur[k] = S[k * 256 + blockIdx.x];
  __syncthreads();
  const int chunk = (E + 255) / 256;
  const int s = blockIdx.x * chunk;
  const int e = min(E, s + chunk);
  for (int i = s + t; i < e; i += 256) {
    const int sv = src[i];
    const int d = dst[i];
    atomicAdd(&deg_out[sv], 1);
    const int pos = atomicAdd(&cur[d >> 8], 1);
    tmp[pos] = sv | ((d & 255) << 20);
  }
}

// passD: per-bucket: deg_in hist + LDS scan -> rowStart, norms, edgeSrc scatter.
__global__ void k_passD(const int* __restrict__ tmp, const int* __restrict__ S,
                        int nbuck, int N, int E, const int* __restrict__ deg_out,
                        int* __restrict__ rowStart, int* __restrict__ edgeSrc,
                        float* __restrict__ ns, float* __restrict__ nd) {
  __shared__ int h[256];
  __shared__ int ex[256];
  __shared__ int c[256];
  const int t = threadIdx.x;
  const int k = blockIdx.x;
  const int bs = S[k * 256];
  const int be = (k + 1 < nbuck) ? S[(k + 1) * 256] : E;
  h[t] = 0;
  __syncthreads();
  for (int i = bs + t; i < be; i += 256) atomicAdd(&h[tmp[i] >> 20], 1);
  __syncthreads();
  const int node = k * 256 + t;
  const int cnt = h[t];
  ex[t] = cnt;
  __syncthreads();
  for (int off = 1; off < 256; off <<= 1) {
    int u = (t >= off) ? ex[t - off] : 0;
    __syncthreads();
    ex[t] += u;
    __syncthreads();
  }
  const int excl = ex[t] - cnt;
  if (node < N) {
    rowStart[node] = bs + excl;
    nd[node] = rsqrtf((float)(cnt > 0 ? cnt : 1));
    int dov = deg_out[node];
    if (dov <= 0) dov = 1;
    ns[node] = rsqrtf((float)dov);
  }
  c[t] = bs + excl;
  __syncthreads();
  for (int i = bs + t; i < be; i += 256) {
    const int v = tmp[i];
    const int pos = atomicAdd(&c[v >> 20], 1);
    edgeSrc[pos] = v & 0xFFFFF;
  }
}

// ---------------- MFMA GEMM -> QUARTER-MAJOR output ----------------
// out_q[nt] = cols [nt*16, nt*16+16): out[nt*N*16 + row*16 + col16]
// QIN: input h is quarter-major (N x 16 x 4 arrays); else natural row-major.
template <int K, bool FIRST, bool SCALE, bool QIN>
__global__ void k_gemm(const void* __restrict__ hin, const void* __restrict__ Wv,
                       const int* __restrict__ flag, const float* __restrict__ norm_src,
                       int N, unsigned short* __restrict__ out) {
  const bool isb = (*flag != 0);
  const int lane = threadIdx.x & 63;
  const int quad = lane >> 4;
  const int l16 = lane & 15;
  constexpr int KT = K / 32;
  const int N16 = N * 16;

  bf16x8 Bf[KT][4];
  {
    const unsigned short* Wus = (const unsigned short*)Wv;
    const float* Wf = (const float*)Wv;
#pragma unroll
    for (int kt = 0; kt < KT; ++kt)
#pragma unroll
      for (int nt = 0; nt < 4; ++nt)
#pragma unroll
        for (int j = 0; j < 8; ++j) {
          const int k = kt * 32 + quad * 8 + j;
          const int n = nt * 16 + l16;
          const float w = isb ? b2f(Wus[k * 64 + n]) : Wf[k * 64 + n];
          Bf[kt][nt][j] = (short)f2b(w);
        }
  }
  const int wid = (blockIdx.x * blockDim.x + threadIdx.x) >> 6;
  const int nw = (gridDim.x * blockDim.x) >> 6;
  const int G = (N + 15) >> 4;
  for (int g = wid; g < G; g += nw) {
    int rowA = (g << 4) + l16;
    if (rowA >= N) rowA = N - 1;
    f32x4 acc[4] = {{0.f, 0.f, 0.f, 0.f}, {0.f, 0.f, 0.f, 0.f},
                    {0.f, 0.f, 0.f, 0.f}, {0.f, 0.f, 0.f, 0.f}};
#pragma unroll
    for (int kt = 0; kt < KT; ++kt) {
      const int koff = kt * 32 + quad * 8;
      bf16x8 Af;
      if (FIRST && !isb) {
        const float* hp = (const float*)hin + (size_t)rowA * K + koff;
        const float4 u0 = *(const float4*)hp;
        const float4 u1 = *(const float4*)(hp + 4);
        Af[0] = (short)f2b(u0.x); Af[1] = (short)f2b(u0.y);
        Af[2] = (short)f2b(u0.z); Af[3] = (short)f2b(u0.w);
        Af[4] = (short)f2b(u1.x); Af[5] = (short)f2b(u1.y);
        Af[6] = (short)f2b(u1.z); Af[7] = (short)f2b(u1.w);
      } else if (QIN) {
        const int qq = kt * 2 + (quad >> 1);
        const int offq = (quad & 1) * 8;
        Af = *(const bf16x8*)((const unsigned short*)hin +
                              (size_t)qq * N16 + (size_t)rowA * 16 + offq);
      } else {
        Af = *(const bf16x8*)((const unsigned short*)hin + (size_t)rowA * K + koff);
      }
      acc[0] = __builtin_amdgcn_mfma_f32_16x16x32_bf16(Af, Bf[kt][0], acc[0], 0, 0, 0);
      acc[1] = __builtin_amdgcn_mfma_f32_16x16x32_bf16(Af, Bf[kt][1], acc[1], 0, 0, 0);
      acc[2] = __builtin_amdgcn_mfma_f32_16x16x32_bf16(Af, Bf[kt][2], acc[2], 0, 0, 0);
      acc[3] = __builtin_amdgcn_mfma_f32_16x16x32_bf16(Af, Bf[kt][3], acc[3], 0, 0, 0);
    }
    const int rowD = (g << 4) + quad * 4;
#pragma unroll
    for (int r = 0; r < 4; ++r) {
      if (rowD + r < N) {
        const float f = SCALE ? norm_src[rowD + r] : 1.0f;
#pragma unroll
        for (int nt = 0; nt < 4; ++nt)
          out[(size_t)nt * N16 + (size_t)(rowD + r) * 16 + l16] =
              f2b(SCALE ? acc[nt][r] * f : acc[nt][r]);
      }
    }
  }
}

// ============== quarter-sliced aggregation ==============
// Outer loop q=0..3: all resident waves sweep the same 3.2 MB projQ slice
// (fits each XCD's 4 MiB L2). Inner: round-6 shape — 2 nodes/wave interleaved,
// 8 edge slots (eo=lane>>3), cg=lane&7 -> ushort2 cols [cg*2, cg*2+1] of quarter.
template <bool LAST>
__global__ void k_aggQ(const unsigned short* __restrict__ projQ,
                       const int* __restrict__ edgeSrc, const int* __restrict__ rowStart,
                       const float* __restrict__ norm_dst, const float* __restrict__ norm_src,
                       const void* __restrict__ bias, const int* __restrict__ flag,
                       int N, void* __restrict__ outp) {
  const bool isb = (*flag != 0);
  const int lane = threadIdx.x & 63;
  const int eo = lane >> 3;
  const int cg = lane & 7;
  const int wave = (blockIdx.x * blockDim.x + threadIdx.x) >> 6;
  const int nwaves = (gridDim.x * blockDim.x) >> 6;
  const int N16 = N * 16;
  for (int q = 0; q < 4; ++q) {
    const unsigned short* proj = projQ + (size_t)q * N16;
    float bc0, bc1;
    if (isb) {
      const unsigned short* bb = (const unsigned short*)bias;
      bc0 = b2f(bb[q * 16 + cg * 2]); bc1 = b2f(bb[q * 16 + cg * 2 + 1]);
    } else {
      const float* bb = (const float*)bias;
      bc0 = bb[q * 16 + cg * 2]; bc1 = bb[q * 16 + cg * 2 + 1];
    }
    for (int n0 = wave * 2; n0 < N; n0 += nwaves * 2) {
      const int n1 = n0 + 1;
      const int s0 = rowStart[n0];
      const int mid = rowStart[n0 + 1];
      const int e1 = (n1 < N) ? rowStart[n0 + 2] : mid;
      int base0 = s0, cnt0 = mid - s0;
      int base1 = mid, cnt1 = e1 - mid;
      float a0x = 0.f, a0y = 0.f, a1x = 0.f, a1y = 0.f;
      while (cnt0 > 0 || cnt1 > 0) {
        const int take0 = cnt0 < 64 ? cnt0 : 64;
        const int take1 = cnt1 < 64 ? cnt1 : 64;
        const int idx0 = (lane < take0) ? edgeSrc[base0 + lane] : 0;
        const int idx1 = (lane < take1) ? edgeSrc[base1 + lane] : 0;
        const int tmax = take0 > take1 ? take0 : take1;
        for (int c = 0; c < tmax; c += 8) {
          const int sl = c + eo;
          if (c < take0) {
            const int sn = __shfl(idx0, sl, 64);
            if (sl < take0) {
              const ushort2 v = *(const ushort2*)(proj + (size_t)sn * 16 + cg * 2);
              a0x += b2f(v.x); a0y += b2f(v.y);
            }
          }
          if (c < take1) {
            const int sn = __shfl(idx1, sl, 64);
            if (sl < take1) {
              const ushort2 v = *(const ushort2*)(proj + (size_t)sn * 16 + cg * 2);
              a1x += b2f(v.x); a1y += b2f(v.y);
            }
          }
        }
        base0 += take0; cnt0 -= take0;
        base1 += take1; cnt1 -= take1;
      }
      a0x += __shfl_xor(a0x, 8, 64); a0y += __shfl_xor(a0y, 8, 64);
      a1x += __shfl_xor(a1x, 8, 64); a1y += __shfl_xor(a1y, 8, 64);
      a0x += __shfl_xor(a0x, 16, 64); a0y += __shfl_xor(a0y, 16, 64);
      a1x += __shfl_xor(a1x, 16, 64); a1y += __shfl_xor(a1y, 16, 64);
      a0x += __shfl_xor(a0x, 32, 64); a0y += __shfl_xor(a0y, 32, 64);
      a1x += __shfl_xor(a1x, 32, 64); a1y += __shfl_xor(a1y, 32, 64);
      if (eo < 2) {
        const int n = (eo == 0) ? n0 : n1;
        if (n < N) {
          const float nd = norm_dst[n];
          float r0 = fmaxf(fmaf((eo == 0) ? a0x : a1x, nd, bc0), 0.f);
          float r1 = fmaxf(fmaf((eo == 0) ? a0y : a1y, nd, bc1), 0.f);
          if (!LAST) {
            const float e = norm_src[n];
            r0 *= e; r1 *= e;
            ushort2 o; o.x = f2b(r0); o.y = f2b(r1);
            *(ushort2*)((unsigned short*)outp + (size_t)q * N16 + (size_t)n * 16 + cg * 2) = o;
          } else if (isb) {
            ushort2 o; o.x = f2b(r0); o.y = f2b(r1);
            *(ushort2*)((unsigned short*)outp + (size_t)n * 64 + q * 16 + cg * 2) = o;
          } else {
            float2 o; o.x = r0; o.y = r1;
            *(float2*)((float*)outp + (size_t)n * 64 + q * 16 + cg * 2) = o;
          }
        }
      }
    }
  }
}

extern "C" void kernel_launch(void* const* d_in, const int* in_sizes, int n_in,
                              void* d_out, int out_size, void* d_ws, size_t ws_size,
                              hipStream_t stream) {
  const void* features = d_in[0];
  const void* W0 = d_in[1];
  const void* b0 = d_in[2];
  const void* W1 = d_in[3];
  const void* b1 = d_in[4];
  const void* W2 = d_in[5];
  const void* b2 = d_in[6];
  const int* src = (const int*)d_in[7];
  const int* dst = (const int*)d_in[8];
  const int N = in_sizes[0] / 128;
  const int E = in_sizes[7];
  const int NBUCK = (N + 255) >> 8;
  const int M = NBUCK * 256;

  char* w = (char*)d_ws;
  size_t off = 0;
  auto alloc = [&](size_t bytes) {
    void* p = w + off;
    off = (off + bytes + 255) & ~(size_t)255;
    return p;
  };
  int* deg_out = (int*)alloc((size_t)N * 4);
  const size_t zero_bytes = off;  // only deg_out needs zeroing
  int* flag = (int*)alloc(4);
  int* rowStart = (int*)alloc((size_t)(N + 1) * 4);
  int* counts = (int*)alloc((size_t)M * 4);
  int* bsums = (int*)alloc(512 * 4);
  float* norm_src = (float*)alloc((size_t)N * 4);
  float* norm_dst = (float*)alloc((size_t)N * 4);
  int* tmp = (int*)alloc((size_t)E * 4);
  int* edgeSrc = (int*)alloc((size_t)E * 4);
  unsigned short* projA = (unsigned short*)alloc((size_t)N * 64 * 2);  // bf16, quarter-major
  unsigned short* hB = (unsigned short*)d_out;  // inter-layer h (bf16, quarter-major)

  hipMemsetAsync(d_ws, 0, zero_bytes, stream);

  const size_t lds_nb = (size_t)NBUCK * 4;
  const int GB = ((N + 15) / 16 + 3) / 4;

  // CSR build
  k_passA<<<257, 256, lds_nb, stream>>>(dst, E, NBUCK, counts,
                                        (const unsigned short*)features, flag);
  const int NB2 = (M + 255) / 256;  // == NBUCK
  k_scan1<<<NB2, 256, 0, stream>>>(counts, M, bsums);
  k_scan2<<<1, 512, 0, stream>>>(bsums, NB2, rowStart, N, E);
  k_scan3<<<NB2, 256, 0, stream>>>(counts, M, bsums);
  k_passC<<<256, 256, lds_nb, stream>>>(src, dst, E, NBUCK, counts, tmp, deg_out);
  k_passD<<<NBUCK, 256, 0, stream>>>(tmp, counts, NBUCK, N, E, deg_out,
                                     rowStart, edgeSrc, norm_src, norm_dst);

  const int AB = 2048;  // persistent waves: q-phases roughly machine-synchronized
  // layer 0 (ns folded into gemm0 epilogue; quarter-major proj out)
  k_gemm<128, true, true, false><<<GB, 256, 0, stream>>>(features, W0, flag, norm_src, N, projA);
  k_aggQ<false><<<AB, 256, 0, stream>>>(projA, edgeSrc, rowStart, norm_dst, norm_src, b0, flag, N, hB);
  // layer 1 (h pre-scaled by ns in agg epilogue; quarter-major in/out)
  k_gemm<64, false, false, true><<<GB, 256, 0, stream>>>(hB, W1, flag, nullptr, N, projA);
  k_aggQ<false><<<AB, 256, 0, stream>>>(projA, edgeSrc, rowStart, norm_dst, norm_src, b1, flag, N, hB);
  // layer 2 -> d_out (natural layout)
  k_gemm<64, false, false, true><<<GB, 256, 0, stream>>>(hB, W2, flag, nullptr, N, projA);
  k_aggQ<true><<<AB, 256, 0, stream>>>(projA, edgeSrc, rowStart, norm_dst, norm_src, b2, flag, N, d_out);
}

// Round 10
// 380.027 us; speedup vs baseline: 2.5348x; 1.4079x over previous
//
#include <hip/hip_runtime.h>
#include <hip/hip_bf16.h>

typedef __hip_bfloat16 bf16;
typedef __attribute__((ext_vector_type(8))) short bf16x8;
typedef __attribute__((ext_vector_type(8))) unsigned short u16x8;
typedef __attribute__((ext_vector_type(4))) float f32x4;

__device__ __forceinline__ float b2f(unsigned short u) {
  return __uint_as_float(((unsigned)u) << 16);
}
__device__ __forceinline__ unsigned short f2b(float x) {
  bf16 h = __float2bfloat16(x);
  return *reinterpret_cast<unsigned short*>(&h);
}

// ============== passA: coarse hist of dst AND src + dtype probe ==============
// counts[0..M): dst buckets (counts[k*256+b]); counts[M..2M): src buckets.
__global__ void k_passA(const int* __restrict__ src, const int* __restrict__ dst, int E,
                        int nbuck, int M, int* __restrict__ counts,
                        const unsigned short* __restrict__ raw, int* __restrict__ flag) {
  if (blockIdx.x == 256) {
    __shared__ int sbad, snz;
    const int t = threadIdx.x;
    if (t == 0) { sbad = 0; snz = 0; }
    __syncthreads();
    const unsigned short u = raw[t];
    const float a = fabsf(b2f(u));
    if (!(a < 100.f)) atomicAdd(&sbad, 1);
    if (((t & 1) == 0) && u != 0) atomicAdd(&snz, 1);
    __syncthreads();
    if (t == 0) flag[0] = (sbad == 0 && snz > 0) ? 1 : 0;
    return;
  }
  extern __shared__ int lh[];  // lh1[nbuck] then lh2[nbuck]
  int* lh1 = lh;
  int* lh2 = lh + nbuck;
  const int t = threadIdx.x;
  for (int k = t; k < 2 * nbuck; k += 256) lh[k] = 0;
  __syncthreads();
  const int chunk = (E + 255) / 256;
  const int s = blockIdx.x * chunk;
  const int e = min(E, s + chunk);
  for (int i = s + t; i < e; i += 256) {
    atomicAdd(&lh1[dst[i] >> 8], 1);
    atomicAdd(&lh2[src[i] >> 8], 1);
  }
  __syncthreads();
  for (int k = t; k < nbuck; k += 256) {
    counts[k * 256 + blockIdx.x] = lh1[k];
    counts[M + k * 256 + blockIdx.x] = lh2[k];
  }
}

// exclusive scan over 2M ints
__global__ void k_scan1(const int* __restrict__ a, int M2, int* __restrict__ bsums) {
  __shared__ int sdata[256];
  int i = blockIdx.x * 256 + threadIdx.x;
  int v = (i < M2) ? a[i] : 0;
  sdata[threadIdx.x] = v;
  __syncthreads();
  for (int s = 128; s > 0; s >>= 1) {
    if (threadIdx.x < s) sdata[threadIdx.x] += sdata[threadIdx.x + s];
    __syncthreads();
  }
  if (threadIdx.x == 0) bsums[blockIdx.x] = sdata[0];
}

__global__ void k_scan2(int* __restrict__ bsums, int nb, int* __restrict__ rowStart,
                        int N, int E) {
  __shared__ int s[1024];
  const int t = threadIdx.x;
  const int v = (t < nb) ? bsums[t] : 0;
  s[t] = v;
  __syncthreads();
  for (int off = 1; off < 1024; off <<= 1) {
    int u = (t >= off) ? s[t - off] : 0;
    __syncthreads();
    s[t] += u;
    __syncthreads();
  }
  if (t < nb) bsums[t] = s[t] - v;  // exclusive
  if (t == 0) rowStart[N] = E;
}

__global__ void k_scan3(int* __restrict__ a, int M2, const int* __restrict__ bsums) {
  __shared__ int sdata[256];
  int i = blockIdx.x * 256 + threadIdx.x;
  int v = (i < M2) ? a[i] : 0;
  sdata[threadIdx.x] = v;
  __syncthreads();
  for (int off = 1; off < 256; off <<= 1) {
    int t = (threadIdx.x >= off) ? sdata[threadIdx.x - off] : 0;
    __syncthreads();
    sdata[threadIdx.x] += t;
    __syncthreads();
  }
  if (i < M2) a[i] = bsums[blockIdx.x] + sdata[threadIdx.x] - v;  // exclusive
}

// passC: dual scatter via LDS cursors — ZERO global atomics.
// tmp[pos1] = src | ((dst&255)<<20)  (dst-bucket-grouped, 4B)
// tmp2[pos2-E] = src&255             (src-bucket-grouped, 1B)
__global__ void k_passC(const int* __restrict__ src, const int* __restrict__ dst, int E,
                        int nbuck, int M, const int* __restrict__ S,
                        int* __restrict__ tmp, unsigned char* __restrict__ tmp2) {
  extern __shared__ int cur[];  // cur1[nbuck], cur2[nbuck]
  int* cur1 = cur;
  int* cur2 = cur + nbuck;
  const int t = threadIdx.x;
  for (int k = t; k < nbuck; k += 256) {
    cur1[k] = S[k * 256 + blockIdx.x];
    cur2[k] = S[M + k * 256 + blockIdx.x];
  }
  __syncthreads();
  const int chunk = (E + 255) / 256;
  const int s = blockIdx.x * chunk;
  const int e = min(E, s + chunk);
  for (int i = s + t; i < e; i += 256) {
    const int sv = src[i];
    const int d = dst[i];
    const int pos1 = atomicAdd(&cur1[d >> 8], 1);
    tmp[pos1] = sv | ((d & 255) << 20);
    const int pos2 = atomicAdd(&cur2[sv >> 8], 1);
    tmp2[pos2 - E] = (unsigned char)(sv & 255);
  }
}

// passD: per bucket k: (1) src-side byte hist -> deg_out -> ns;
//        (2) dst-side hist + scan -> rowStart, nd, edgeSrc scatter.
__global__ void k_passD(const int* __restrict__ tmp, const unsigned char* __restrict__ tmp2,
                        const int* __restrict__ S, int nbuck, int M, int N, int E,
                        int* __restrict__ rowStart, int* __restrict__ edgeSrc,
                        float* __restrict__ ns, float* __restrict__ nd) {
  __shared__ int h[256];
  __shared__ int ex[256];
  __shared__ int c[256];
  const int t = threadIdx.x;
  const int k = blockIdx.x;
  const int node = k * 256 + t;
  // ---- phase 1: src-side (deg_out -> ns) ----
  const int bs2 = S[M + k * 256] - E;
  const int be2 = (k + 1 < nbuck) ? (S[M + (k + 1) * 256] - E) : E;
  h[t] = 0;
  __syncthreads();
  for (int i = bs2 + t; i < be2; i += 256) atomicAdd(&h[tmp2[i]], 1);
  __syncthreads();
  if (node < N) {
    int dov = h[t];
    if (dov <= 0) dov = 1;
    ns[node] = rsqrtf((float)dov);
  }
  __syncthreads();
  // ---- phase 2: dst-side (rowStart, nd, edgeSrc) ----
  const int bs = S[k * 256];
  const int be = (k + 1 < nbuck) ? S[(k + 1) * 256] : E;
  h[t] = 0;
  __syncthreads();
  for (int i = bs + t; i < be; i += 256) atomicAdd(&h[tmp[i] >> 20], 1);
  __syncthreads();
  const int cnt = h[t];
  ex[t] = cnt;
  __syncthreads();
  for (int off = 1; off < 256; off <<= 1) {
    int u = (t >= off) ? ex[t - off] : 0;
    __syncthreads();
    ex[t] += u;
    __syncthreads();
  }
  const int excl = ex[t] - cnt;
  if (node < N) {
    rowStart[node] = bs + excl;
    nd[node] = rsqrtf((float)(cnt > 0 ? cnt : 1));
  }
  c[t] = bs + excl;
  __syncthreads();
  for (int i = bs + t; i < be; i += 256) {
    const int v = tmp[i];
    const int pos = atomicAdd(&c[v >> 20], 1);
    edgeSrc[pos] = v & 0xFFFFF;
  }
}

// ---------------- MFMA GEMM: out[r][c] = bf16( [ns[r]*] sum_k h[r][k]*W[k][c] ) ------
template <int K, bool FIRST, bool SCALE>
__global__ void k_gemm(const void* __restrict__ hin, const void* __restrict__ Wv,
                       const int* __restrict__ flag, const float* __restrict__ norm_src,
                       int N, unsigned short* __restrict__ out) {
  const bool isb = (*flag != 0);
  const int lane = threadIdx.x & 63;
  const int quad = lane >> 4;
  const int l16 = lane & 15;
  constexpr int KT = K / 32;

  bf16x8 Bf[KT][4];
  {
    const unsigned short* Wus = (const unsigned short*)Wv;
    const float* Wf = (const float*)Wv;
#pragma unroll
    for (int kt = 0; kt < KT; ++kt)
#pragma unroll
      for (int nt = 0; nt < 4; ++nt)
#pragma unroll
        for (int j = 0; j < 8; ++j) {
          const int k = kt * 32 + quad * 8 + j;
          const int n = nt * 16 + l16;
          const float w = isb ? b2f(Wus[k * 64 + n]) : Wf[k * 64 + n];
          Bf[kt][nt][j] = (short)f2b(w);
        }
  }
  const int wid = (blockIdx.x * blockDim.x + threadIdx.x) >> 6;
  const int nw = (gridDim.x * blockDim.x) >> 6;
  const int G = (N + 15) >> 4;
  for (int g = wid; g < G; g += nw) {
    int rowA = (g << 4) + l16;
    if (rowA >= N) rowA = N - 1;
    f32x4 acc[4] = {{0.f, 0.f, 0.f, 0.f}, {0.f, 0.f, 0.f, 0.f},
                    {0.f, 0.f, 0.f, 0.f}, {0.f, 0.f, 0.f, 0.f}};
#pragma unroll
    for (int kt = 0; kt < KT; ++kt) {
      const int koff = kt * 32 + quad * 8;
      bf16x8 Af;
      if (FIRST && !isb) {
        const float* hp = (const float*)hin + (size_t)rowA * K + koff;
        const float4 u0 = *(const float4*)hp;
        const float4 u1 = *(const float4*)(hp + 4);
        Af[0] = (short)f2b(u0.x); Af[1] = (short)f2b(u0.y);
        Af[2] = (short)f2b(u0.z); Af[3] = (short)f2b(u0.w);
        Af[4] = (short)f2b(u1.x); Af[5] = (short)f2b(u1.y);
        Af[6] = (short)f2b(u1.z); Af[7] = (short)f2b(u1.w);
      } else {
        Af = *(const bf16x8*)((const unsigned short*)hin + (size_t)rowA * K + koff);
      }
      acc[0] = __builtin_amdgcn_mfma_f32_16x16x32_bf16(Af, Bf[kt][0], acc[0], 0, 0, 0);
      acc[1] = __builtin_amdgcn_mfma_f32_16x16x32_bf16(Af, Bf[kt][1], acc[1], 0, 0, 0);
      acc[2] = __builtin_amdgcn_mfma_f32_16x16x32_bf16(Af, Bf[kt][2], acc[2], 0, 0, 0);
      acc[3] = __builtin_amdgcn_mfma_f32_16x16x32_bf16(Af, Bf[kt][3], acc[3], 0, 0, 0);
    }
    const int rowD = (g << 4) + quad * 4;
#pragma unroll
    for (int r = 0; r < 4; ++r) {
      if (rowD + r < N) {
        const float f = SCALE ? norm_src[rowD + r] : 1.0f;
        const size_t o = (size_t)(rowD + r) * 64 + l16;
#pragma unroll
        for (int nt = 0; nt < 4; ++nt)
          out[o + nt * 16] = f2b(SCALE ? acc[nt][r] * f : acc[nt][r]);
      }
    }
  }
}

// ---------------- aggregation (round-6 proven): 2 nodes/wave interleaved ----------
template <bool LAST>
__global__ void k_aggregate(const unsigned short* __restrict__ proj,
                            const int* __restrict__ edgeSrc, const int* __restrict__ rowStart,
                            const float* __restrict__ norm_dst, const float* __restrict__ norm_src,
                            const void* __restrict__ bias, const int* __restrict__ flag,
                            int N, void* __restrict__ outp) {
  const bool isb = (*flag != 0);
  const int lane = threadIdx.x & 63;
  const int eo = lane >> 3;
  const int cg = lane & 7;
  float bcol[8];
#pragma unroll
  for (int j = 0; j < 8; ++j)
    bcol[j] = isb ? b2f(((const unsigned short*)bias)[cg * 8 + j])
                  : ((const float*)bias)[cg * 8 + j];
  const int wave = (blockIdx.x * blockDim.x + threadIdx.x) >> 6;
  const int nwaves = (gridDim.x * blockDim.x) >> 6;
  for (int n0 = wave * 2; n0 < N; n0 += nwaves * 2) {
    const int n1 = n0 + 1;
    const int s0 = rowStart[n0];
    const int mid = rowStart[n0 + 1];
    const int e1 = (n1 < N) ? rowStart[n0 + 2] : mid;
    int base0 = s0, cnt0 = mid - s0;
    int base1 = mid, cnt1 = e1 - mid;
    float a0[8] = {0.f, 0.f, 0.f, 0.f, 0.f, 0.f, 0.f, 0.f};
    float a1[8] = {0.f, 0.f, 0.f, 0.f, 0.f, 0.f, 0.f, 0.f};
    while (cnt0 > 0 || cnt1 > 0) {
      const int take0 = cnt0 < 64 ? cnt0 : 64;
      const int take1 = cnt1 < 64 ? cnt1 : 64;
      const int idx0 = (lane < take0) ? edgeSrc[base0 + lane] : 0;
      const int idx1 = (lane < take1) ? edgeSrc[base1 + lane] : 0;
      const int tmax = take0 > take1 ? take0 : take1;
      for (int c = 0; c < tmax; c += 8) {
        const int sl = c + eo;
        if (c < take0) {
          const int sn = __shfl(idx0, sl, 64);
          if (sl < take0) {
            const u16x8 v = *(const u16x8*)(proj + (size_t)sn * 64 + cg * 8);
#pragma unroll
            for (int j = 0; j < 8; ++j) a0[j] += b2f(v[j]);
          }
        }
        if (c < take1) {
          const int sn = __shfl(idx1, sl, 64);
          if (sl < take1) {
            const u16x8 v = *(const u16x8*)(proj + (size_t)sn * 64 + cg * 8);
#pragma unroll
            for (int j = 0; j < 8; ++j) a1[j] += b2f(v[j]);
          }
        }
      }
      base0 += take0; cnt0 -= take0;
      base1 += take1; cnt1 -= take1;
    }
#pragma unroll
    for (int j = 0; j < 8; ++j) {
      a0[j] += __shfl_xor(a0[j], 8, 64);
      a0[j] += __shfl_xor(a0[j], 16, 64);
      a0[j] += __shfl_xor(a0[j], 32, 64);
      a1[j] += __shfl_xor(a1[j], 8, 64);
      a1[j] += __shfl_xor(a1[j], 16, 64);
      a1[j] += __shfl_xor(a1[j], 32, 64);
    }
    if (eo < 2) {
      const int n = (eo == 0) ? n0 : n1;
      if (n < N) {
        const float nd = norm_dst[n];
        float r[8];
#pragma unroll
        for (int j = 0; j < 8; ++j) {
          const float av = (eo == 0) ? a0[j] : a1[j];
          r[j] = fmaxf(fmaf(av, nd, bcol[j]), 0.f);
        }
        if (!LAST) {
          const float esc = norm_src[n];
#pragma unroll
          for (int j = 0; j < 8; ++j) r[j] *= esc;
        }
        if (LAST && !isb) {
          float* of = (float*)outp + (size_t)n * 64 + cg * 8;
          float4 o0; o0.x = r[0]; o0.y = r[1]; o0.z = r[2]; o0.w = r[3];
          float4 o1; o1.x = r[4]; o1.y = r[5]; o1.z = r[6]; o1.w = r[7];
          *(float4*)of = o0;
          *(float4*)(of + 4) = o1;
        } else {
          u16x8 o;
#pragma unroll
          for (int j = 0; j < 8; ++j) o[j] = f2b(r[j]);
          *(u16x8*)((unsigned short*)outp + (size_t)n * 64 + cg * 8) = o;
        }
      }
    }
  }
}

extern "C" void kernel_launch(void* const* d_in, const int* in_sizes, int n_in,
                              void* d_out, int out_size, void* d_ws, size_t ws_size,
                              hipStream_t stream) {
  const void* features = d_in[0];
  const void* W0 = d_in[1];
  const void* b0 = d_in[2];
  const void* W1 = d_in[3];
  const void* b1 = d_in[4];
  const void* W2 = d_in[5];
  const void* b2 = d_in[6];
  const int* src = (const int*)d_in[7];
  const int* dst = (const int*)d_in[8];
  const int N = in_sizes[0] / 128;
  const int E = in_sizes[7];
  const int NBUCK = (N + 255) >> 8;  // 391
  const int M = NBUCK * 256;
  const int M2 = 2 * M;

  char* w = (char*)d_ws;
  size_t off = 0;
  auto alloc = [&](size_t bytes) {
    void* p = w + off;
    off = (off + bytes + 255) & ~(size_t)255;
    return p;
  };
  int* flag = (int*)alloc(4);
  int* rowStart = (int*)alloc((size_t)(N + 1) * 4);
  int* counts = (int*)alloc((size_t)M2 * 4);
  int* bsums = (int*)alloc(1024 * 4);
  float* norm_src = (float*)alloc((size_t)N * 4);
  float* norm_dst = (float*)alloc((size_t)N * 4);
  int* tmp = (int*)alloc((size_t)E * 4);
  unsigned char* tmp2 = (unsigned char*)alloc((size_t)E);
  int* edgeSrc = (int*)alloc((size_t)E * 4);
  unsigned short* projA = (unsigned short*)alloc((size_t)N * 64 * 2);  // bf16
  unsigned short* hB = (unsigned short*)d_out;  // inter-layer h (bf16) in d_out

  const size_t lds_nb = (size_t)NBUCK * 2 * 4;  // dual hist/cursors
  const int GB = ((N + 15) / 16 + 3) / 4;

  // CSR build — zero global atomics end-to-end, no memset needed.
  k_passA<<<257, 256, lds_nb, stream>>>(src, dst, E, NBUCK, M, counts,
                                        (const unsigned short*)features, flag);
  const int NB2 = (M2 + 255) / 256;  // == 2*NBUCK = 782
  k_scan1<<<NB2, 256, 0, stream>>>(counts, M2, bsums);
  k_scan2<<<1, 1024, 0, stream>>>(bsums, NB2, rowStart, N, E);
  k_scan3<<<NB2, 256, 0, stream>>>(counts, M2, bsums);
  k_passC<<<256, 256, lds_nb, stream>>>(src, dst, E, NBUCK, M, counts, tmp, tmp2);
  k_passD<<<NBUCK, 256, 0, stream>>>(tmp, tmp2, counts, NBUCK, M, N, E,
                                     rowStart, edgeSrc, norm_src, norm_dst);

  const int AB = ((N + 1) / 2 + 3) / 4;  // 2 nodes/wave, 4 waves/block
  // layer 0 (ns folded into gemm0 epilogue)
  k_gemm<128, true, true><<<GB, 256, 0, stream>>>(features, W0, flag, norm_src, N, projA);
  k_aggregate<false><<<AB, 256, 0, stream>>>(projA, edgeSrc, rowStart, norm_dst, norm_src, b0, flag, N, hB);
  // layer 1 (h pre-scaled by ns in agg epilogue)
  k_gemm<64, false, false><<<GB, 256, 0, stream>>>(hB, W1, flag, nullptr, N, projA);
  k_aggregate<false><<<AB, 256, 0, stream>>>(projA, edgeSrc, rowStart, norm_dst, norm_src, b1, flag, N, hB);
  // layer 2 -> d_out
  k_gemm<64, false, false><<<GB, 256, 0, stream>>>(hB, W2, flag, nullptr, N, projA);
  k_aggregate<true><<<AB, 256, 0, stream>>>(projA, edgeSrc, rowStart, norm_dst, norm_src, b2, flag, N, d_out);
}